// Round 2
// baseline (426.108 us; speedup 1.0000x reference)
//
#include <hip/hip_runtime.h>

// Reference collapses: softmax row-sums are exactly 1, and einsum 'bqk,bvd->bqd'
// contracts k and v independently, so out[b,q,d] = sum_n v[b,n,d] (q-independent).
//   colsum[b,ch] = sum_n GN(x)[b,n,ch]   (phase 1, per-group atomics)
//   S[b,d]       = dot(Wv[d,:], colsum[b,:]) + 1024*bv[d]          (phase 2)
//   out[b,d,:]   = dot(Wo[d,:], S[b,:]) + bo[d]  broadcast over hw (phase 3)
// Wq/bq/Wk/bk are provably dead (they only enter via softmax row-sum == 1).
//
// Round 2: hipLaunchCooperativeKernel does not survive the harness's graph
// capture (round 1: output stayed zero). Same fused structure, but with a
// hand-rolled software grid barrier: 512 blocks x 256 thr, __launch_bounds__
// (256,2) -> exactly 2 blocks/CU on 256 CUs, all co-resident (LDS 4.2 KB,
// VGPR << 128), so the spin barrier cannot deadlock. Barrier counters are
// zeroed by the same hipMemsetAsync that zeroes colsum. Dispatches: 4 -> 2.

#define BATCH 16
#define CH    1024
#define NHW   1024
#define G     32
#define NPG   32
#define EPG   (NPG*CH)
#define EPSV  1e-5f
#define GRID  (BATCH*G)   // 512 blocks

__device__ __forceinline__ void grid_barrier(int* ctr)
{
    __threadfence();                 // release: flush this block's writes (agent scope)
    __syncthreads();
    if (threadIdx.x == 0) {
        __hip_atomic_fetch_add(ctr, 1, __ATOMIC_RELEASE, __HIP_MEMORY_SCOPE_AGENT);
        while (__hip_atomic_load(ctr, __ATOMIC_ACQUIRE, __HIP_MEMORY_SCOPE_AGENT) < GRID)
            __builtin_amdgcn_s_sleep(2);
    }
    __syncthreads();
    __threadfence();                 // acquire: invalidate stale cache lines before reading peers' data
}

__global__ __launch_bounds__(256, 2) void fused_all(
    const float* __restrict__ x, const float* __restrict__ gamma,
    const float* __restrict__ beta,
    const float* __restrict__ Wv, const float* __restrict__ bv,
    const float* __restrict__ Wo, const float* __restrict__ bo,
    float* __restrict__ colsum, float* __restrict__ S,
    float* __restrict__ out, int* __restrict__ bar)
{
    const int blk  = blockIdx.x;
    const int t    = threadIdx.x;
    const int lane = t & 63, wave = t >> 6;

    // ---- phase 1: GN stats + colsum contribution (block = (b,g)) ----
    // Identical to the harness-verified k1_fused. Block (b,g) owns ALL data of
    // group (b,g): computes mean/var/inv locally, atomicAdds inv*pch[ch]+cshare
    // into colsum (cshare sums exactly to the GN constant over the 32 g-blocks).
    {
        const int b  = blk >> 5, g = blk & 31;
        const int n4 = t & 7;                 // which float4 of the group's 32 n's
        const int c0 = t >> 3;                // starting channel 0..31
        __shared__ float pch[CH];             // gamma-weighted per-channel partials
        __shared__ float r1[4], r2[4], rb[4];

        const float4* xg = reinterpret_cast<const float4*>(x + (size_t)b * (CH * NHW) + g * NPG);
        const float4  gm = reinterpret_cast<const float4*>(gamma + g * NPG)[n4];

        float s1 = 0.f, s2 = 0.f;
        for (int ch = c0; ch < CH; ch += 32) {
            float4 v = xg[ch * (NHW / 4) + n4];
            s1 += v.x + v.y + v.z + v.w;
            s2 += v.x * v.x + v.y * v.y + v.z * v.z + v.w * v.w;
            float p = v.x * gm.x + v.y * gm.y + v.z * gm.z + v.w * gm.w;
            p += __shfl_xor(p, 1);
            p += __shfl_xor(p, 2);
            p += __shfl_xor(p, 4);
            if (n4 == 0) pch[ch] = p;         // one writer per 8-lane cluster
        }
        float bsum = beta[t] + beta[t + 256] + beta[t + 512] + beta[t + 768];
        #pragma unroll
        for (int m = 1; m < 64; m <<= 1) {
            s1 += __shfl_xor(s1, m); s2 += __shfl_xor(s2, m); bsum += __shfl_xor(bsum, m);
        }
        if (lane == 0) { r1[wave] = s1; r2[wave] = s2; rb[wave] = bsum; }
        __syncthreads();

        const float S1 = r1[0] + r1[1] + r1[2] + r1[3];
        const float S2 = r2[0] + r2[1] + r2[2] + r2[3];
        const float SB = rb[0] + rb[1] + rb[2] + rb[3];
        const float mean = S1 * (1.f / EPG);
        const float var  = S2 * (1.f / EPG) - mean * mean;
        const float inv  = rsqrtf(var + EPSV);
        float sg = gm.x + gm.y + gm.z + gm.w;
        sg += __shfl_xor(sg, 1);
        sg += __shfl_xor(sg, 2);
        sg += __shfl_xor(sg, 4);
        const float cshare = SB * (1.f / 32.f) - inv * mean * sg;

        for (int ch = t; ch < CH; ch += 256)
            atomicAdd(&colsum[b * CH + ch], inv * pch[ch] + cshare);
    }
    grid_barrier(&bar[0]);

    // ---- phase 2: S[b,d] = dot(Wv[d,:], colsum[b,:]) + 1024*bv[d] ----
    // All 512 blocks: 2 rows per block, 2 waves per row (each wave: 8 batches).
    {
        const int d  = blk * 2 + (wave >> 1);
        const int b0 = (wave & 1) * 8;
        const float4* wrow = reinterpret_cast<const float4*>(Wv + (size_t)d * CH);
        const float4* cs4  = reinterpret_cast<const float4*>(colsum);
        float acc[8];
        #pragma unroll
        for (int b = 0; b < 8; b++) acc[b] = 0.f;
        #pragma unroll
        for (int i = 0; i < 4; i++) {
            int e4 = i * 64 + lane;
            float4 w = wrow[e4];
            #pragma unroll
            for (int b = 0; b < 8; b++) {
                float4 c = cs4[(b0 + b) * 256 + e4];
                acc[b] += w.x * c.x + w.y * c.y + w.z * c.z + w.w * c.w;
            }
        }
        #pragma unroll
        for (int b = 0; b < 8; b++) {
            float a = acc[b];
            #pragma unroll
            for (int m = 1; m < 64; m <<= 1) a += __shfl_xor(a, m);
            if (lane == 0) S[(b0 + b) * CH + d] = a + (float)NHW * bv[d];
        }
    }
    grid_barrier(&bar[1]);

    // ---- phase 3: out[b,d,:] = dot(Wo[d,:], S[b,:]) + bo[d], bcast over hw ----
    // 2048 waves: 2 waves per row d (same block -> duplicated Wo row read is an
    // L1 hit), each writes half of the 1024-wide hw range per (b,d).
    {
        const int wid  = blk * 4 + wave;
        const int d    = wid >> 1;
        const int half = wid & 1;
        const float4* wrow = reinterpret_cast<const float4*>(Wo + (size_t)d * CH);
        const float4* s4   = reinterpret_cast<const float4*>(S);
        float acc[BATCH];
        #pragma unroll
        for (int b = 0; b < BATCH; b++) acc[b] = 0.f;
        #pragma unroll
        for (int i = 0; i < 4; i++) {
            int e4 = i * 64 + lane;
            float4 w = wrow[e4];
            #pragma unroll
            for (int b = 0; b < BATCH; b++) {
                float4 c = s4[b * 256 + e4];
                acc[b] += w.x * c.x + w.y * c.y + w.z * c.z + w.w * c.w;
            }
        }
        #pragma unroll
        for (int b = 0; b < BATCH; b++) {     // full butterfly: all lanes hold the sum
            #pragma unroll
            for (int m = 1; m < 64; m <<= 1) acc[b] += __shfl_xor(acc[b], m);
        }
        const float bod = bo[d];
        #pragma unroll
        for (int b = 0; b < BATCH; b++) {
            float val = acc[b] + bod;
            float4 v4 = make_float4(val, val, val, val);
            float4* op = reinterpret_cast<float4*>(out + ((size_t)b * CH + d) * NHW) + half * 128;
            #pragma unroll
            for (int i = 0; i < 2; i++) op[i * 64 + lane] = v4;  // 1 KiB contiguous per wave-store
        }
    }
}

extern "C" void kernel_launch(void* const* d_in, const int* in_sizes, int n_in,
                              void* d_out, int out_size, void* d_ws, size_t ws_size,
                              hipStream_t stream)
{
    const float* x     = (const float*)d_in[0];
    const float* gamma = (const float*)d_in[1];
    const float* beta  = (const float*)d_in[2];
    // d_in[3..6] = Wq, bq, Wk, bk: provably dead (softmax row-sum == 1)
    const float* Wv    = (const float*)d_in[7];
    const float* bv    = (const float*)d_in[8];
    const float* Wo    = (const float*)d_in[9];
    const float* bo    = (const float*)d_in[10];
    float* out = (float*)d_out;

    char* ws = (char*)d_ws;
    float* colsum = (float*)ws;                       // 16*1024 f = 64 KiB
    int*   bar    = (int*)(ws + 65536);               // 2 barrier counters (+pad)
    float* Sbuf   = (float*)(ws + 65536 + 256);       // 16*1024 f = 64 KiB

    // One memset zeroes colsum AND the barrier counters.
    hipMemsetAsync(ws, 0, 65536 + 256, stream);
    fused_all<<<GRID, 256, 0, stream>>>(x, gamma, beta, Wv, bv, Wo, bo,
                                        colsum, Sbuf, out, bar);
}

// Round 4
// 176.901 us; speedup vs baseline: 2.4087x; 2.4087x over previous
//
#include <hip/hip_runtime.h>

// Reference collapses: softmax row-sums are exactly 1, and einsum 'bqk,bvd->bqd'
// contracts k and v independently, so out[b,q,d] = sum_n v[b,n,d] (q-independent).
//   colsum[b,ch] = sum_n GN(x)[b,n,ch]   (phase 1, per-group atomics)
//   S[b,d]       = dot(Wv[d,:], colsum[b,:]) + 1024*bv[d]          (phase 2)
//   out[b,d,:]   = dot(Wo[d,:], S[b,:]) + bo[d]  broadcast over hw (phase 3)
// Wq/bq/Wk/bk are provably dead (they only enter via softmax row-sum == 1).
//
// Round 4 (= round 3 resubmit + per-batch barriers; round 3 died to container
// infra, never ran). Fence-free cross-block handshake: all cross-block data
// (colsum, S, counters) moves only through relaxed agent-scope atomics
// (performed at the coherence point; producers write-through, consumers bypass
// stale L1/L2). No __threadfence -> no buffer_wbl2/buffer_inv storm (round 2's
// 320us pathology). __syncthreads() drains vmcnt(0) before the arrive-add, so
// counter==N => all prior coherent writes of arrived blocks are visible.
//
// KEY refinement: dependencies are batch-local. colsum[b,:] is produced by
// blocks (b, g=0..31) and consumed by blocks (b, rg=0..31) — the same 32
// blocks; likewise S[b,:]. So both grid barriers become 16 independent
// per-batch barriers (32 arrivals each): minimal skew, batches pipeline
// through the phases, 32 pollers per counter instead of 512.

#define BATCH 16
#define CH    1024
#define NHW   1024
#define G     32
#define NPG   32
#define EPG   (NPG*CH)
#define EPSV  1e-5f
#define GRID  (BATCH*G)   // 512 blocks = 2/CU, co-resident via __launch_bounds__(256,2)

__device__ __forceinline__ void coh_store_f32(float* p, float v) {
    __hip_atomic_store((unsigned*)p, __float_as_uint(v), __ATOMIC_RELAXED, __HIP_MEMORY_SCOPE_AGENT);
}
// coherent 8-byte load (2 floats), bypassing potentially-stale L1/L2
__device__ __forceinline__ void coh_load_f32x2(const float* p, float* d0, float* d1) {
    unsigned long long u = __hip_atomic_load((const unsigned long long*)p,
                                             __ATOMIC_RELAXED, __HIP_MEMORY_SCOPE_AGENT);
    *d0 = __uint_as_float((unsigned)(u & 0xffffffffu));
    *d1 = __uint_as_float((unsigned)(u >> 32));
}

// Fence-free per-batch barrier: relaxed arrive + relaxed poll by thread 0.
// __syncthreads() emits s_waitcnt vmcnt(0) before s_barrier, so every thread's
// coherent/atomic writes have reached the coherence point before the arrive.
__device__ __forceinline__ void batch_barrier(int* ctr, int expected)
{
    __syncthreads();
    if (threadIdx.x == 0) {
        __hip_atomic_fetch_add(ctr, 1, __ATOMIC_RELAXED, __HIP_MEMORY_SCOPE_AGENT);
        while (__hip_atomic_load(ctr, __ATOMIC_RELAXED, __HIP_MEMORY_SCOPE_AGENT) < expected)
            __builtin_amdgcn_s_sleep(1);
    }
    __syncthreads();
}

__global__ __launch_bounds__(256, 2) void fused_all(
    const float* __restrict__ x, const float* __restrict__ gamma,
    const float* __restrict__ beta,
    const float* __restrict__ Wv, const float* __restrict__ bv,
    const float* __restrict__ Wo, const float* __restrict__ bo,
    float* __restrict__ colsum, float* __restrict__ S,
    float* __restrict__ out, int* __restrict__ bar0, int* __restrict__ bar1)
{
    const int blk  = blockIdx.x;
    const int t    = threadIdx.x;
    const int lane = t & 63, wave = t >> 6;
    const int b    = blk >> 5;            // batch: same meaning in all phases

    __shared__ float smem[CH];            // pch (phase 1) / cs (phase 2) / sv (phase 3)
    __shared__ float r1[4], r2[4], rb[4];

    // ---- phase 1: GN stats + colsum contribution (block = (b, g)) ----
    // Identical math to the harness-verified k1_fused. atomicAdd is a
    // coherence-point RMW, so consumers reading colsum coherently need no fence.
    {
        const int g  = blk & 31;
        const int n4 = t & 7;                 // which float4 of the group's 32 n's
        const int c0 = t >> 3;                // starting channel 0..31

        const float4* xg = reinterpret_cast<const float4*>(x + (size_t)b * (CH * NHW) + g * NPG);
        const float4  gm = reinterpret_cast<const float4*>(gamma + g * NPG)[n4];

        float s1 = 0.f, s2 = 0.f;
        for (int ch = c0; ch < CH; ch += 32) {
            float4 v = xg[ch * (NHW / 4) + n4];
            s1 += v.x + v.y + v.z + v.w;
            s2 += v.x * v.x + v.y * v.y + v.z * v.z + v.w * v.w;
            float p = v.x * gm.x + v.y * gm.y + v.z * gm.z + v.w * gm.w;
            p += __shfl_xor(p, 1);
            p += __shfl_xor(p, 2);
            p += __shfl_xor(p, 4);
            if (n4 == 0) smem[ch] = p;        // one writer per 8-lane cluster
        }
        float bsum = beta[t] + beta[t + 256] + beta[t + 512] + beta[t + 768];
        #pragma unroll
        for (int m = 1; m < 64; m <<= 1) {
            s1 += __shfl_xor(s1, m); s2 += __shfl_xor(s2, m); bsum += __shfl_xor(bsum, m);
        }
        if (lane == 0) { r1[wave] = s1; r2[wave] = s2; rb[wave] = bsum; }
        __syncthreads();

        const float S1 = r1[0] + r1[1] + r1[2] + r1[3];
        const float S2 = r2[0] + r2[1] + r2[2] + r2[3];
        const float SB = rb[0] + rb[1] + rb[2] + rb[3];
        const float mean = S1 * (1.f / EPG);
        const float var  = S2 * (1.f / EPG) - mean * mean;
        const float inv  = rsqrtf(var + EPSV);
        float sg = gm.x + gm.y + gm.z + gm.w;
        sg += __shfl_xor(sg, 1);
        sg += __shfl_xor(sg, 2);
        sg += __shfl_xor(sg, 4);
        const float cshare = SB * (1.f / 32.f) - inv * mean * sg;

        for (int ch = t; ch < CH; ch += 256)
            atomicAdd(&colsum[b * CH + ch], inv * smem[ch] + cshare);
    }
    batch_barrier(&bar0[b * 32], G);   // wait for the 32 g-blocks of THIS batch

    // ---- phase 2: S[b,d] = dot(Wv[d,:], colsum[b,:]) + 1024*bv[d] ----
    // Block = (b, rowgroup rg) -> rows d = rg*32 .. rg*32+31. Only 4 KB of
    // coherent loads per block (colsum[b,:] -> LDS); Wv rows are normal cached
    // loads (16x reuse across the 16 b-blocks that share a rowgroup).
    {
        const int rg = blk & 31;
        const float* src = colsum + b * CH + t * 4;
        float a0, a1, a2, a3;
        coh_load_f32x2(src,     &a0, &a1);
        coh_load_f32x2(src + 2, &a2, &a3);
        smem[t * 4 + 0] = a0; smem[t * 4 + 1] = a1;
        smem[t * 4 + 2] = a2; smem[t * 4 + 3] = a3;
        __syncthreads();

        const int d0 = rg * 32 + wave * 8;
        const float4* cs4 = reinterpret_cast<const float4*>(smem);
        #pragma unroll
        for (int j = 0; j < 8; j++) {
            const int d = d0 + j;
            const float4* wrow = reinterpret_cast<const float4*>(Wv + (size_t)d * CH);
            float a = 0.f;
            #pragma unroll
            for (int i = 0; i < 4; i++) {
                int e4 = i * 64 + lane;
                float4 w = wrow[e4];
                float4 c = cs4[e4];
                a += w.x * c.x + w.y * c.y + w.z * c.z + w.w * c.w;
            }
            #pragma unroll
            for (int m = 1; m < 64; m <<= 1) a += __shfl_xor(a, m);
            if (lane == 0)
                coh_store_f32(&S[b * CH + d], a + (float)NHW * bv[d]);  // write-through
        }
    }
    batch_barrier(&bar1[b * 32], G);   // wait for the 32 rg-blocks of THIS batch

    // ---- phase 3: out[b,d,:] = dot(Wo[d,:], S[b,:]) + bo[d], bcast over hw ----
    // Same partition: block = (b, rg), 32 rows; coherent-load S[b,:] (4 KB) to
    // LDS; Wo cached; out written with plain stores (flushed at kernel end).
    {
        const int rg = blk & 31;
        const float* src = S + b * CH + t * 4;
        float a0, a1, a2, a3;
        coh_load_f32x2(src,     &a0, &a1);
        coh_load_f32x2(src + 2, &a2, &a3);
        smem[t * 4 + 0] = a0; smem[t * 4 + 1] = a1;
        smem[t * 4 + 2] = a2; smem[t * 4 + 3] = a3;
        __syncthreads();

        const int d0 = rg * 32 + wave * 8;
        const float4* s4 = reinterpret_cast<const float4*>(smem);
        #pragma unroll
        for (int j = 0; j < 8; j++) {
            const int d = d0 + j;
            const float4* wrow = reinterpret_cast<const float4*>(Wo + (size_t)d * CH);
            float a = 0.f;
            #pragma unroll
            for (int i = 0; i < 4; i++) {
                int e4 = i * 64 + lane;
                float4 w = wrow[e4];
                float4 c = s4[e4];
                a += w.x * c.x + w.y * c.y + w.z * c.z + w.w * c.w;
            }
            #pragma unroll
            for (int m = 1; m < 64; m <<= 1) a += __shfl_xor(a, m);  // all lanes hold sum
            const float val = a + bo[d];
            float4 v4 = make_float4(val, val, val, val);
            float4* op = reinterpret_cast<float4*>(out + ((size_t)b * CH + d) * NHW);
            #pragma unroll
            for (int i = 0; i < 4; i++) op[i * 64 + lane] = v4;  // 1 KiB contiguous per wave-store
        }
    }
}

extern "C" void kernel_launch(void* const* d_in, const int* in_sizes, int n_in,
                              void* d_out, int out_size, void* d_ws, size_t ws_size,
                              hipStream_t stream)
{
    const float* x     = (const float*)d_in[0];
    const float* gamma = (const float*)d_in[1];
    const float* beta  = (const float*)d_in[2];
    // d_in[3..6] = Wq, bq, Wk, bk: provably dead (softmax row-sum == 1)
    const float* Wv    = (const float*)d_in[7];
    const float* bv    = (const float*)d_in[8];
    const float* Wo    = (const float*)d_in[9];
    const float* bo    = (const float*)d_in[10];
    float* out = (float*)d_out;

    char* ws = (char*)d_ws;
    float* colsum = (float*)ws;                       // 16*1024 f = 64 KiB
    int*   bar0   = (int*)(ws + 65536);               // 16 counters, 128B apart
    int*   bar1   = (int*)(ws + 65536 + 2048);        // 16 counters, 128B apart
    float* Sbuf   = (float*)(ws + 65536 + 4096);      // 16*1024 f = 64 KiB

    // One memset zeroes colsum AND all barrier counters.
    hipMemsetAsync(ws, 0, 65536 + 4096, stream);
    fused_all<<<GRID, 256, 0, stream>>>(x, gamma, beta, Wv, bv, Wo, bo,
                                        colsum, Sbuf, out, bar0, bar1);
}

// Round 5
// 158.077 us; speedup vs baseline: 2.6956x; 1.1191x over previous
//
#include <hip/hip_runtime.h>

// Reference collapses: softmax row-sums are exactly 1, and einsum 'bqk,bvd->bqd'
// contracts k and v independently, so out[b,q,d] = sum_n v[b,n,d] (q-independent).
//   colsum[b,ch] = sum_n GN(x)[b,n,ch]   (phase 1, per-group atomics)
//   S[b,d]       = dot(Wv[d,:], colsum[b,:]) + 1024*bv[d]          (phase 2)
//   out[b,d,:]   = dot(Wo[d,:], S[b,:]) + bo[d]  broadcast over hw (phase 3)
// Wq/bq/Wk/bk are provably dead (they only enter via softmax row-sum == 1).
//
// Round 5. Round 4 (fence-free barriers) passed at 69us kernel time but was
// LATENCY-BOUND: VALUBusy 7%, HBM 550 GB/s, occupancy 19% — only 2 waves/SIMD
// (launch_bounds(256,2)) and ~4 loads in flight (VGPR=52). This round keeps
// the identical barrier/coherence protocol (proven correct) and attacks
// latency hiding:
//   (a) 512-thread blocks: same 512-block-grid partition (barrier logic
//       untouched, 32 arrivals/batch) but 16 waves/CU co-resident.
//   (b) phase-1 inner loop restructured into explicit 8-deep load batches so
//       8 independent global_load_dwordx4 are in flight before first use.

#define BATCH 16
#define CH    1024
#define NHW   1024
#define G     32
#define NPG   32
#define EPG   (NPG*CH)
#define EPSV  1e-5f
#define GRID  (BATCH*G)   // 512 blocks = 2/CU capacity, co-resident (rounds 2/4 empirical)
#define TPB   512

__device__ __forceinline__ void coh_store_f32(float* p, float v) {
    __hip_atomic_store((unsigned*)p, __float_as_uint(v), __ATOMIC_RELAXED, __HIP_MEMORY_SCOPE_AGENT);
}
// coherent 8-byte load (2 floats), bypassing potentially-stale L1/L2
__device__ __forceinline__ void coh_load_f32x2(const float* p, float* d0, float* d1) {
    unsigned long long u = __hip_atomic_load((const unsigned long long*)p,
                                             __ATOMIC_RELAXED, __HIP_MEMORY_SCOPE_AGENT);
    *d0 = __uint_as_float((unsigned)(u & 0xffffffffu));
    *d1 = __uint_as_float((unsigned)(u >> 32));
}

// Fence-free per-batch barrier: relaxed arrive + relaxed poll by thread 0.
// __syncthreads() emits s_waitcnt vmcnt(0) before s_barrier, so every thread's
// coherent/atomic writes have reached the coherence point before the arrive.
__device__ __forceinline__ void batch_barrier(int* ctr, int expected)
{
    __syncthreads();
    if (threadIdx.x == 0) {
        __hip_atomic_fetch_add(ctr, 1, __ATOMIC_RELAXED, __HIP_MEMORY_SCOPE_AGENT);
        while (__hip_atomic_load(ctr, __ATOMIC_RELAXED, __HIP_MEMORY_SCOPE_AGENT) < expected)
            __builtin_amdgcn_s_sleep(1);
    }
    __syncthreads();
}

__global__ __launch_bounds__(TPB, 4) void fused_all(
    const float* __restrict__ x, const float* __restrict__ gamma,
    const float* __restrict__ beta,
    const float* __restrict__ Wv, const float* __restrict__ bv,
    const float* __restrict__ Wo, const float* __restrict__ bo,
    float* __restrict__ colsum, float* __restrict__ S,
    float* __restrict__ out, int* __restrict__ bar0, int* __restrict__ bar1)
{
    const int blk  = blockIdx.x;
    const int t    = threadIdx.x;
    const int lane = t & 63, wave = t >> 6;   // 8 waves
    const int b    = blk >> 5;                // batch: same meaning in all phases

    __shared__ float smem[CH];                // pch (p1) / cs (p2) / sv (p3)
    __shared__ float r1[8], r2[8], rb[8];

    // ---- phase 1: GN stats + colsum contribution (block = (b, g)) ----
    // Same math as the harness-verified k1_fused, 512 threads: c0 covers 64
    // channels, 16 ch-iterations, issued as 2 batches of 8 independent loads.
    {
        const int g  = blk & 31;
        const int n4 = t & 7;                 // which float4 of the group's 32 n's
        const int c0 = t >> 3;                // starting channel 0..63

        const float4* xg = reinterpret_cast<const float4*>(x + (size_t)b * (CH * NHW) + g * NPG);
        const float4  gm = reinterpret_cast<const float4*>(gamma + g * NPG)[n4];

        float s1 = 0.f, s2 = 0.f;
        #pragma unroll
        for (int half = 0; half < 2; half++) {
            float4 vb[8];
            #pragma unroll
            for (int k = 0; k < 8; k++)       // 8 independent loads in flight
                vb[k] = xg[(c0 + (half * 8 + k) * 64) * (NHW / 4) + n4];
            #pragma unroll
            for (int k = 0; k < 8; k++) {
                const float4 v = vb[k];
                const int ch = c0 + (half * 8 + k) * 64;
                s1 += v.x + v.y + v.z + v.w;
                s2 += v.x * v.x + v.y * v.y + v.z * v.z + v.w * v.w;
                float p = v.x * gm.x + v.y * gm.y + v.z * gm.z + v.w * gm.w;
                p += __shfl_xor(p, 1);
                p += __shfl_xor(p, 2);
                p += __shfl_xor(p, 4);
                if (n4 == 0) smem[ch] = p;    // one writer per 8-lane cluster
            }
        }
        float bsum = beta[t] + beta[t + 512];
        #pragma unroll
        for (int m = 1; m < 64; m <<= 1) {
            s1 += __shfl_xor(s1, m); s2 += __shfl_xor(s2, m); bsum += __shfl_xor(bsum, m);
        }
        if (lane == 0) { r1[wave] = s1; r2[wave] = s2; rb[wave] = bsum; }
        __syncthreads();

        float S1 = 0.f, S2 = 0.f, SB = 0.f;
        #pragma unroll
        for (int w = 0; w < 8; w++) { S1 += r1[w]; S2 += r2[w]; SB += rb[w]; }
        const float mean = S1 * (1.f / EPG);
        const float var  = S2 * (1.f / EPG) - mean * mean;
        const float inv  = rsqrtf(var + EPSV);
        float sg = gm.x + gm.y + gm.z + gm.w;   // this group's 32 gammas
        sg += __shfl_xor(sg, 1);
        sg += __shfl_xor(sg, 2);
        sg += __shfl_xor(sg, 4);
        const float cshare = SB * (1.f / 32.f) - inv * mean * sg;

        #pragma unroll
        for (int ch = t; ch < CH; ch += TPB)    // 2 iterations
            atomicAdd(&colsum[b * CH + ch], inv * smem[ch] + cshare);
    }
    batch_barrier(&bar0[b * 32], G);   // wait for the 32 g-blocks of THIS batch

    // ---- phase 2: S[b,d] = dot(Wv[d,:], colsum[b,:]) + 1024*bv[d] ----
    // Block = (b, rowgroup rg) -> rows d = rg*32..rg*32+31 (4 rows per wave).
    // Only 4 KB of coherent loads per block (colsum[b,:] -> LDS); Wv rows are
    // normal cached loads (16x reuse across the 16 b-blocks per rowgroup).
    {
        const int rg = blk & 31;
        float a0, a1;
        coh_load_f32x2(colsum + b * CH + t * 2, &a0, &a1);
        smem[t * 2 + 0] = a0; smem[t * 2 + 1] = a1;
        __syncthreads();

        const int d0 = rg * 32 + wave * 4;
        const float4* cs4 = reinterpret_cast<const float4*>(smem);
        #pragma unroll
        for (int j = 0; j < 4; j++) {
            const int d = d0 + j;
            const float4* wrow = reinterpret_cast<const float4*>(Wv + (size_t)d * CH);
            float a = 0.f;
            #pragma unroll
            for (int i = 0; i < 4; i++) {
                int e4 = i * 64 + lane;
                float4 w = wrow[e4];
                float4 c = cs4[e4];
                a += w.x * c.x + w.y * c.y + w.z * c.z + w.w * c.w;
            }
            #pragma unroll
            for (int m = 1; m < 64; m <<= 1) a += __shfl_xor(a, m);
            if (lane == 0)
                coh_store_f32(&S[b * CH + d], a + (float)NHW * bv[d]);  // write-through
        }
    }
    batch_barrier(&bar1[b * 32], G);   // wait for the 32 rg-blocks of THIS batch

    // ---- phase 3: out[b,d,:] = dot(Wo[d,:], S[b,:]) + bo[d], bcast over hw ----
    // Same partition; coherent-load S[b,:] (4 KB) to LDS; Wo cached; out
    // written with plain stores (flushed at kernel end).
    {
        const int rg = blk & 31;
        float a0, a1;
        coh_load_f32x2(S + b * CH + t * 2, &a0, &a1);
        smem[t * 2 + 0] = a0; smem[t * 2 + 1] = a1;
        __syncthreads();

        const int d0 = rg * 32 + wave * 4;
        const float4* s4 = reinterpret_cast<const float4*>(smem);
        #pragma unroll
        for (int j = 0; j < 4; j++) {
            const int d = d0 + j;
            const float4* wrow = reinterpret_cast<const float4*>(Wo + (size_t)d * CH);
            float a = 0.f;
            #pragma unroll
            for (int i = 0; i < 4; i++) {
                int e4 = i * 64 + lane;
                float4 w = wrow[e4];
                float4 c = s4[e4];
                a += w.x * c.x + w.y * c.y + w.z * c.z + w.w * c.w;
            }
            #pragma unroll
            for (int m = 1; m < 64; m <<= 1) a += __shfl_xor(a, m);  // all lanes hold sum
            const float val = a + bo[d];
            float4 v4 = make_float4(val, val, val, val);
            float4* op = reinterpret_cast<float4*>(out + ((size_t)b * CH + d) * NHW);
            #pragma unroll
            for (int i = 0; i < 4; i++) op[i * 64 + lane] = v4;  // 1 KiB contiguous per wave-store
        }
    }
}

extern "C" void kernel_launch(void* const* d_in, const int* in_sizes, int n_in,
                              void* d_out, int out_size, void* d_ws, size_t ws_size,
                              hipStream_t stream)
{
    const float* x     = (const float*)d_in[0];
    const float* gamma = (const float*)d_in[1];
    const float* beta  = (const float*)d_in[2];
    // d_in[3..6] = Wq, bq, Wk, bk: provably dead (softmax row-sum == 1)
    const float* Wv    = (const float*)d_in[7];
    const float* bv    = (const float*)d_in[8];
    const float* Wo    = (const float*)d_in[9];
    const float* bo    = (const float*)d_in[10];
    float* out = (float*)d_out;

    char* ws = (char*)d_ws;
    float* colsum = (float*)ws;                       // 16*1024 f = 64 KiB
    int*   bar0   = (int*)(ws + 65536);               // 16 counters, 128B apart
    int*   bar1   = (int*)(ws + 65536 + 2048);        // 16 counters, 128B apart
    float* Sbuf   = (float*)(ws + 65536 + 4096);      // 16*1024 f = 64 KiB

    // One memset zeroes colsum AND all barrier counters.
    hipMemsetAsync(ws, 0, 65536 + 4096, stream);
    fused_all<<<GRID, TPB, 0, stream>>>(x, gamma, beta, Wv, bv, Wo, bo,
                                        colsum, Sbuf, out, bar0, bar1);
}